// Round 8
// baseline (508.677 us; speedup 1.0000x reference)
//
#include <hip/hip_runtime.h>
#include <hip/hip_bf16.h>

// FFB encoder, MI355X. Round 15: dual point-group pipeline (T15 pattern).
// r14 (best, 188us): body is serial high-MFMA -> VALU -> mid-MFMA -> VALU
// within a wave; 2.4 waves/SIMD can't fill the antiphase (24% no-issue).
// This round: each wave owns mt=sub for TWO 32-pt groups (A,B) sharing one
// W register set (mh/ml/hfr reused -> zero extra weight traffic/regs).
// Issue order high(A,B) -> midA -> midB -> bufFinish -> epi(A+B merged):
// epi-A VALU overlaps mid-B MFMA execution IN-WAVE. WG=256 covers 64 pts,
// grid 2048, barriers/point halved again. LDS = X dbuf for 2 quads = 64KB
// exactly (EP back to L2; A/B share every EP load -> half r10's EP traffic).
// lb(256,2): ~230 unified regs < 256 budget. Kill signal: WRITE >85MB=spill.

typedef __bf16 bf16_t;
typedef __attribute__((ext_vector_type(8))) __bf16 bf16x8;
typedef __attribute__((ext_vector_type(4))) float f32x4;
typedef __attribute__((ext_vector_type(16))) float f32x16;

#define C56R 8.9126768f               // 56 / (2*pi)
#define INV7 0.14285714285714285f

// ws layout (bytes) — frag-linear, unchanged from r4-r14
#define OFF_WMF   0        // mid W hi  [7][4mt][8kc][64lane][8bf16]
#define OFF_WMFLO 229376   // mid W lo
#define OFF_WHF   458752   // high W hi
#define OFF_EPM   688128   // [7][2hf][4mt][16r] float4 {ap0, ap1, C56R*bm, C56R*bh}

union ChunkU { bf16x8 v; unsigned int d[4]; };

__device__ __forceinline__ unsigned short bfbits(float x) {
  bf16_t b = (bf16_t)x;
  return __builtin_bit_cast(unsigned short, b);
}
__device__ __forceinline__ float bf2f(unsigned short u) {
  return __builtin_bit_cast(float, (unsigned int)u << 16);
}
__device__ __forceinline__ void pack2(float v0, float v1,
                                      unsigned int& ph, unsigned int& pl) {
  unsigned short h0 = bfbits(v0), h1 = bfbits(v1);
  ph = (unsigned int)h0 | ((unsigned int)h1 << 16);
  float l0 = v0 - bf2f(h0), l1 = v1 - bf2f(h1);
  pl = (unsigned int)bfbits(l0) | ((unsigned int)bfbits(l1) << 16);
}

__global__ void ffb_prep(const float* __restrict__ ffnA, const float* __restrict__ sigma,
                         const float* __restrict__ Wm, const float* __restrict__ bm,
                         const float* __restrict__ Wh, const float* __restrict__ bh,
                         unsigned char* __restrict__ ws) {
  int i = blockIdx.x * 256 + threadIdx.x;  // 448*256 = 114688 exactly
  bf16_t* wmf = (bf16_t*)(ws + OFF_WMF);
  bf16_t* wml = (bf16_t*)(ws + OFF_WMFLO);
  bf16_t* whf = (bf16_t*)(ws + OFF_WHF);
  {
    // fragment reorder: [it][mt][kc][lane][j]
    int j    = i & 7;
    int lane = (i >> 3) & 63;
    int kc   = (i >> 9) & 7;
    int mt   = (i >> 12) & 3;
    int it   = i >> 14;                       // 0..6
    int ho   = (mt << 5) + (lane & 31);
    int hin  = (kc << 4) + ((lane >> 5) << 3) + j;
    int src  = (it << 14) + (ho << 7) + hin;
    float w  = Wm[src];
    bf16_t h = (bf16_t)w;
    wmf[i] = h;
    wml[i] = (bf16_t)(w - (float)h);
    whf[i] = (bf16_t)Wh[src];
  }
  if (i < 896) {
    int r  = i & 15;
    int mt = (i >> 4) & 3;
    int hf = (i >> 6) & 1;
    int it = i >> 7;                          // 0..6
    int h  = (mt << 5) + (r & 3) + ((r >> 2) << 3) + (hf << 2);
    float sg = sigma[it];
    f32x4 e;
    e.x = ffnA[it * 256 + h] * sg;
    e.y = ffnA[it * 256 + 128 + h] * sg;
    e.z = C56R * bm[it * 128 + h];
    e.w = C56R * bh[it * 128 + h];
    ((f32x4*)(ws + OFF_EPM))[i] = e;
  }
}

__launch_bounds__(256, 2)
__global__ void ffb_main(const float* __restrict__ pos,
                         const float* __restrict__ gfeat,
                         const float* __restrict__ W0,
                         const float* __restrict__ b0,
                         const unsigned char* __restrict__ ws,
                         float* __restrict__ out) {
  // LDS: X double-buffer for 2 quads:
  // [dbuf:2][quad:2][hi/lo][kc:8][lane:64][16B] = 64KB exactly
  __shared__ __align__(16) unsigned char sX[65536];

  const int tid  = threadIdx.x;
  const int L    = tid & 63;
  const int sub  = tid >> 6;        // wave 0..3 = mt tile owned
  const int p    = L & 31;
  const int hf   = L >> 5;
  const int nA   = (blockIdx.x << 6) + p;
  const int nB   = nA + 32;

  const bf16_t* __restrict__ WMH = (const bf16_t*)(ws + OFF_WMF);
  const bf16_t* __restrict__ WML = (const bf16_t*)(ws + OFF_WMFLO);
  const bf16_t* __restrict__ WHF = (const bf16_t*)(ws + OFF_WHF);
  const f32x4*  __restrict__ EPM = (const f32x4*)(ws + OFF_EPM);
  const float*  __restrict__ EPW = (const float*)(ws + OFF_EPM);

  // ---- prefetch mid-W level 0 into registers (shared by groups A and B)
  bf16x8 mh[8], ml[8], hfr[8];
  {
    const bf16_t* wh0 = WMH + (sub << 12) + (L << 3);
    const bf16_t* wl0 = WML + (sub << 12) + (L << 3);
    #pragma unroll
    for (int kc = 0; kc < 8; ++kc) {
      mh[kc] = *(const bf16x8*)(wh0 + (kc << 9));
      ml[kc] = *(const bf16x8*)(wl0 + (kc << 9));
    }
  }

  const float pA0 = pos[nA * 3 + 0], pA1 = pos[nA * 3 + 1], pA2 = pos[nA * 3 + 2];
  const float pB0 = pos[nB * 3 + 0], pB1 = pos[nB * 3 + 1], pB2 = pos[nB * 3 + 2];
  if (sub == 0 && hf == 0) {
    out[(size_t)nA * 131 + 0] = (pA0 + 1.f) * 0.5f;
    out[(size_t)nA * 131 + 1] = (pA1 + 1.f) * 0.5f;
    out[(size_t)nA * 131 + 2] = (pA2 + 1.f) * 0.5f;
    out[(size_t)nB * 131 + 0] = (pB0 + 1.f) * 0.5f;
    out[(size_t)nB * 131 + 1] = (pB1 + 1.f) * 0.5f;
    out[(size_t)nB * 131 + 2] = (pB2 + 1.f) * 0.5f;
  }

  // ---- layer 0: fill 2 chunks per quad (B-frag layout) into buffer 0
  #pragma unroll
  for (int q = 0; q < 2; ++q) {
    const float q0 = q ? pB0 : pA0;
    const float q1 = q ? pB1 : pA1;
    const float q2 = q ? pB2 : pA2;
    unsigned char* base = sX + (q << 14);
    #pragma unroll
    for (int cc = 0; cc < 2; ++cc) {
      const int c = (sub << 1) + cc;
      ChunkU chi, clo;
      #pragma unroll
      for (int jp = 0; jp < 4; ++jp) {
        int h0 = (c << 4) + (hf << 3) + 2 * jp;
        float d0 = __builtin_fmaf(q2, W0[h0*3+2], __builtin_fmaf(q1, W0[h0*3+1], q0 * W0[h0*3+0]));
        float d1 = __builtin_fmaf(q2, W0[h0*3+5], __builtin_fmaf(q1, W0[h0*3+4], q0 * W0[h0*3+3]));
        float v0 = __builtin_amdgcn_sinf(C56R * (d0 + b0[h0]));
        float v1 = __builtin_amdgcn_sinf(C56R * (d1 + b0[h0 + 1]));
        pack2(v0, v1, chi.d[jp], clo.d[jp]);
      }
      *(bf16x8*)(base + (c << 10) + (L << 4))        = chi.v;
      *(bf16x8*)(base + 8192 + (c << 10) + (L << 4)) = clo.v;
    }
  }
  __syncthreads();   // X0 (both quads) visible

  f32x16 bufA, bufB;
  #pragma unroll
  for (int r = 0; r < 16; ++r) { bufA[r] = 0.f; bufB[r] = 0.f; }

  #pragma unroll 1
  for (int it = 0; it < 8; ++it) {
    unsigned char* rb  = sX + ((it & 1) << 15);        // X(it), quads 0/1
    unsigned char* wbf = sX + (((it + 1) & 1) << 15);  // X(it+1) target

    // ---- high pass: level it-1, both groups, W in hfr[]
    f32x16 accHA, accHB;
    if (it > 0) {
      #pragma unroll
      for (int r = 0; r < 16; ++r) { accHA[r] = 0.f; accHB[r] = 0.f; }
      #pragma unroll
      for (int kc = 0; kc < 8; ++kc) {
        bf16x8 xA = *(const bf16x8*)(rb + (kc << 10) + (L << 4));
        bf16x8 xB = *(const bf16x8*)(rb + 16384 + (kc << 10) + (L << 4));
        accHA = __builtin_amdgcn_mfma_f32_32x32x16_bf16(hfr[kc], xA, accHA, 0, 0, 0);
        accHB = __builtin_amdgcn_mfma_f32_32x32x16_bf16(hfr[kc], xB, accHB, 0, 0, 0);
      }
    }

    if (it < 7) {
      // prefetch high-W for level it (consumed next body's high pass)
      {
        const bf16_t* wbp = WHF + (it << 14) + (sub << 12) + (L << 3);
        #pragma unroll
        for (int kc = 0; kc < 8; ++kc)
          hfr[kc] = *(const bf16x8*)(wbp + (kc << 9));
      }

      // ---- mid pass: group A then group B (two independent MFMA chains)
      f32x16 accA, accB;
      #pragma unroll
      for (int r = 0; r < 16; ++r) { accA[r] = 0.f; accB[r] = 0.f; }
      #pragma unroll
      for (int kc = 0; kc < 8; ++kc) {
        bf16x8 xhA = *(const bf16x8*)(rb + (kc << 10) + (L << 4));
        bf16x8 xlA = *(const bf16x8*)(rb + 8192 + (kc << 10) + (L << 4));
        accA = __builtin_amdgcn_mfma_f32_32x32x16_bf16(mh[kc], xhA, accA, 0, 0, 0);
        accA = __builtin_amdgcn_mfma_f32_32x32x16_bf16(ml[kc], xhA, accA, 0, 0, 0);
        accA = __builtin_amdgcn_mfma_f32_32x32x16_bf16(mh[kc], xlA, accA, 0, 0, 0);
      }
      #pragma unroll
      for (int kc = 0; kc < 8; ++kc) {
        bf16x8 xhB = *(const bf16x8*)(rb + 16384 + (kc << 10) + (L << 4));
        bf16x8 xlB = *(const bf16x8*)(rb + 24576 + (kc << 10) + (L << 4));
        accB = __builtin_amdgcn_mfma_f32_32x32x16_bf16(mh[kc], xhB, accB, 0, 0, 0);
        accB = __builtin_amdgcn_mfma_f32_32x32x16_bf16(ml[kc], xhB, accB, 0, 0, 0);
        accB = __builtin_amdgcn_mfma_f32_32x32x16_bf16(mh[kc], xlB, accB, 0, 0, 0);
      }

      // prefetch mid-W for level it+1 (crosses 1 barrier)
      if (it < 6) {
        const bf16_t* wh = WMH + ((it + 1) << 14) + (sub << 12) + (L << 3);
        const bf16_t* wl = WML + ((it + 1) << 14) + (sub << 12) + (L << 3);
        #pragma unroll
        for (int kc = 0; kc < 8; ++kc) {
          mh[kc] = *(const bf16x8*)(wh + (kc << 9));
          ml[kc] = *(const bf16x8*)(wl + (kc << 9));
        }
      }

      // buf finish for level it-1 (VALU; overlaps mid-B MFMA execution)
      if (it > 0) {
        const int ebp = ((((it - 1) << 1) + hf) * 4 + sub) * 16;
        #pragma unroll
        for (int r = 0; r < 16; ++r) {
          float cbh = EPW[(ebp + r) * 4 + 3];
          bufA[r] += __builtin_amdgcn_sinf(__builtin_fmaf(accHA[r], C56R, cbh));
          bufB[r] += __builtin_amdgcn_sinf(__builtin_fmaf(accHB[r], C56R, cbh));
        }
      }

      // epilogue merged A+B: one EP load serves both groups; b64 writes
      const float g0A = gfeat[nA * 17 + 3 + 2 * it];
      const float g1A = gfeat[nA * 17 + 4 + 2 * it];
      const float g0B = gfeat[nB * 17 + 3 + 2 * it];
      const float g1B = gfeat[nB * 17 + 4 + 2 * it];
      const int eb = (((it << 1) + hf) * 4 + sub) * 16;
      #pragma unroll
      for (int q = 0; q < 4; ++q) {
        const int r0 = q << 2;
        float vA[4], vB[4];
        #pragma unroll
        for (int k = 0; k < 4; ++k) {
          const int r = r0 + k;
          f32x4 e = EPM[eb + r];
          float sgA = __builtin_amdgcn_sinf(__builtin_amdgcn_fractf(__builtin_fmaf(g1A, e.y, g0A * e.x)));
          float smA = __builtin_amdgcn_sinf(__builtin_fmaf(accA[r], C56R, e.z));
          vA[k] = sgA + smA;
          float sgB = __builtin_amdgcn_sinf(__builtin_amdgcn_fractf(__builtin_fmaf(g1B, e.y, g0B * e.x)));
          float smB = __builtin_amdgcn_sinf(__builtin_fmaf(accB[r], C56R, e.z));
          vB[k] = sgB + smB;
        }
        unsigned int h0, l0, h1, l1;
        pack2(vA[0], vA[1], h0, l0);
        pack2(vA[2], vA[3], h1, l1);
        unsigned long long qhA = (unsigned long long)h0 | ((unsigned long long)h1 << 32);
        unsigned long long qlA = (unsigned long long)l0 | ((unsigned long long)l1 << 32);
        pack2(vB[0], vB[1], h0, l0);
        pack2(vB[2], vB[3], h1, l1);
        unsigned long long qhB = (unsigned long long)h0 | ((unsigned long long)h1 << 32);
        unsigned long long qlB = (unsigned long long)l0 | ((unsigned long long)l1 << 32);
        const int c   = (sub << 1) + (r0 >> 3);
        const int bit = (r0 >> 2) & 1;
        const int off = (c << 10) + ((p + (bit << 5)) << 4) + (hf << 3);
        *(unsigned long long*)(wbf + off)                = qhA;
        *(unsigned long long*)(wbf + 8192 + off)         = qlA;
        *(unsigned long long*)(wbf + 16384 + off)        = qhB;
        *(unsigned long long*)(wbf + 24576 + off)        = qlB;
      }
      __syncthreads();   // X(it+1) both quads visible; only barrier/level
    } else {
      // it == 7: final buf finish (level 6)
      const int ebp = ((((it - 1) << 1) + hf) * 4 + sub) * 16;
      #pragma unroll
      for (int r = 0; r < 16; ++r) {
        float cbh = EPW[(ebp + r) * 4 + 3];
        bufA[r] += __builtin_amdgcn_sinf(__builtin_fmaf(accHA[r], C56R, cbh));
        bufB[r] += __builtin_amdgcn_sinf(__builtin_fmaf(accHB[r], C56R, cbh));
      }
    }
  }

  // ---- final store: this wave's mt=sub rows for both point groups
  float* opA = out + (size_t)nA * 131 + 3;
  float* opB = out + (size_t)nB * 131 + 3;
  #pragma unroll
  for (int r = 0; r < 16; ++r) {
    const int h = (sub << 5) + (r & 3) + ((r >> 2) << 3) + (hf << 2);
    opA[h] = bufA[r] * INV7;
    opB[h] = bufB[r] * INV7;
  }
}

extern "C" void kernel_launch(void* const* d_in, const int* in_sizes, int n_in,
                              void* d_out, int out_size, void* d_ws, size_t ws_size,
                              hipStream_t stream) {
  (void)in_sizes; (void)n_in; (void)out_size; (void)ws_size;
  const float* pos   = (const float*)d_in[0];
  const float* gfeat = (const float*)d_in[1];
  const float* ffnA  = (const float*)d_in[2];
  const float* sigma = (const float*)d_in[3];
  const float* W0    = (const float*)d_in[4];
  const float* b0    = (const float*)d_in[5];
  const float* Wm    = (const float*)d_in[6];
  const float* bm    = (const float*)d_in[7];
  const float* Wh    = (const float*)d_in[8];
  const float* bh    = (const float*)d_in[9];
  float* out = (float*)d_out;
  unsigned char* ws = (unsigned char*)d_ws;

  hipLaunchKernelGGL(ffb_prep, dim3(448), dim3(256), 0, stream,
                     ffnA, sigma, Wm, bm, Wh, bh, ws);
  hipLaunchKernelGGL(ffb_main, dim3(2048), dim3(256), 0, stream,
                     pos, gfeat, W0, b0, ws, out);
}